// Round 1
// baseline (804.984 us; speedup 1.0000x reference)
//
#include <hip/hip_runtime.h>
#include <math.h>

#define N_EMB   1000000
#define D       64
#define E_PAIRS 65536
#define K_NEG   16
#define P_TOTAL (E_PAIRS * (K_NEG + 1))   /* 1114112 */
#define PPB     64                         /* pairs per block */
#define RS      68                         /* LDS row stride (dwords): 16B-aligned, b128-conflict-free */

__global__ __launch_bounds__(256, 2)
void score_kernel(const float* __restrict__ embeds,
                  const int*   __restrict__ pos,
                  const int*   __restrict__ neg,
                  const float* __restrict__ W1,
                  const float* __restrict__ b1,
                  const float* __restrict__ W2,
                  const float* __restrict__ b2,
                  float*       __restrict__ scores)
{
    __shared__ float U[PPB * RS];
    __shared__ float V[PPB * RS];
    __shared__ int   uidx[PPB];
    __shared__ int   vidx[PPB];
    __shared__ float red[4 * PPB];

    const int t = threadIdx.x;
    const int pbase = blockIdx.x * PPB;

    // Stage pair indices
    if (t < PPB) {
        int p = pbase + t;
        int ui, vi;
        if (p < E_PAIRS) {            // block-uniform branch (E_PAIRS % PPB == 0)
            ui = pos[2 * p];
            vi = pos[2 * p + 1];
        } else {
            int q = p - E_PAIRS;
            ui = neg[2 * q];
            vi = neg[2 * q + 1];
        }
        uidx[t] = ui;
        vidx[t] = vi;
    }
    __syncthreads();

    // Coalesced gather: 64 rows x 16 float4 x 2 arrays = 2048 float4 ops, 8/thread.
    // 16 consecutive lanes read one contiguous 256B embedding row.
    #pragma unroll
    for (int k = 0; k < 8; ++k) {
        int flat = t + 256 * k;             // 0..2047
        int arr  = flat >> 10;              // 0 -> U, 1 -> V
        int row  = (flat >> 4) & 63;
        int seg  = flat & 15;
        int idx  = arr ? vidx[row] : uidx[row];
        float4 src = *(const float4*)(embeds + (long long)idx * D + seg * 4);
        float* dst = (arr ? V : U) + row * RS + seg * 4;
        *(float4*)dst = src;
    }
    __syncthreads();

    // Compute: thread -> (pair p, j-chunk jg). jg forced wave-uniform so all
    // W1/b1/W2 accesses scalarize to s_load (scalar pipe, parallel to VALU).
    const int p  = t & 63;
    const int jg = __builtin_amdgcn_readfirstlane(t >> 6);   // 0..3
    const float* __restrict__ W1r = W1 + jg * 16 * 192;

    float h[16];
    #pragma unroll
    for (int jj = 0; jj < 16; ++jj) h[jj] = b1[jg * 16 + jj];

    const float* Up = U + p * RS;
    const float* Vp = V + p * RS;

    #pragma unroll
    for (int ib = 0; ib < 64; ib += 16) {
        float uu[16], vv[16], ww[16];
        #pragma unroll
        for (int c = 0; c < 4; ++c) {
            float4 x = *(const float4*)(Up + ib + c * 4);
            float4 y = *(const float4*)(Vp + ib + c * 4);
            uu[c*4+0] = x.x; uu[c*4+1] = x.y; uu[c*4+2] = x.z; uu[c*4+3] = x.w;
            vv[c*4+0] = y.x; vv[c*4+1] = y.y; vv[c*4+2] = y.z; vv[c*4+3] = y.w;
        }
        #pragma unroll
        for (int ii = 0; ii < 16; ++ii) ww[ii] = uu[ii] * vv[ii];

        #pragma unroll
        for (int jj = 0; jj < 16; ++jj) {
            const float* wrow = W1r + jj * 192 + ib;   // uniform -> s_load
            float acc = h[jj];
            #pragma unroll
            for (int ii = 0; ii < 16; ++ii) {
                acc += uu[ii] * wrow[ii];
                acc += vv[ii] * wrow[64 + ii];
                acc += ww[ii] * wrow[128 + ii];
            }
            h[jj] = acc;
        }
    }

    // Partial dot with W2 over this thread's 16 j's (relu applied here)
    float partial = 0.f;
    #pragma unroll
    for (int jj = 0; jj < 16; ++jj) {
        float hr = h[jj] > 0.f ? h[jj] : 0.f;
        partial += hr * W2[jg * 16 + jj];
    }
    red[jg * 64 + p] = partial;
    __syncthreads();

    if (t < 64) {
        float s   = red[t] + red[64 + t] + red[128 + t] + red[192 + t] + b2[0];
        float sig = 1.f / (1.f + expf(-s));
        scores[pbase + t] = expf(sig);
    }
}

__global__ __launch_bounds__(256)
void reduce_kernel(const float* __restrict__ scores, float* __restrict__ partials)
{
    __shared__ float sdata[256];
    int e = blockIdx.x * 256 + threadIdx.x;    // e in [0, E_PAIRS)
    float pos_s = scores[e];
    const float* ns = scores + E_PAIRS + (size_t)e * K_NEG;
    float nsum = 0.f;
    #pragma unroll
    for (int c = 0; c < 4; ++c) {
        float4 v = *(const float4*)(ns + c * 4);
        nsum += v.x + v.y + v.z + v.w;
    }
    float term = pos_s / (pos_s + nsum + 1e-8f) + 1e-8f;
    sdata[threadIdx.x] = term;
    __syncthreads();
    for (int s = 128; s > 0; s >>= 1) {
        if (threadIdx.x < s) sdata[threadIdx.x] += sdata[threadIdx.x + s];
        __syncthreads();
    }
    if (threadIdx.x == 0) partials[blockIdx.x] = sdata[0];
}

__global__ __launch_bounds__(256)
void final_kernel(const float* __restrict__ partials, float* __restrict__ out)
{
    __shared__ float sdata[256];
    sdata[threadIdx.x] = partials[threadIdx.x];
    __syncthreads();
    for (int s = 128; s > 0; s >>= 1) {
        if (threadIdx.x < s) sdata[threadIdx.x] += sdata[threadIdx.x + s];
        __syncthreads();
    }
    if (threadIdx.x == 0) out[0] = -sdata[0];
}

extern "C" void kernel_launch(void* const* d_in, const int* in_sizes, int n_in,
                              void* d_out, int out_size, void* d_ws, size_t ws_size,
                              hipStream_t stream)
{
    const float* embeds = (const float*)d_in[0];
    const int*   pos    = (const int*)d_in[1];
    const int*   neg    = (const int*)d_in[2];
    const float* W1     = (const float*)d_in[3];
    const float* b1     = (const float*)d_in[4];
    const float* W2     = (const float*)d_in[5];
    const float* b2     = (const float*)d_in[6];
    float* out = (float*)d_out;

    float* scores   = (float*)d_ws;                 // P_TOTAL floats (~4.5 MB)
    float* partials = scores + P_TOTAL;             // 256 floats

    score_kernel<<<P_TOTAL / PPB, 256, 0, stream>>>(embeds, pos, neg, W1, b1, W2, b2, scores);
    reduce_kernel<<<E_PAIRS / 256, 256, 0, stream>>>(scores, partials);
    final_kernel<<<1, 256, 0, stream>>>(partials, out);
}

// Round 2
// 476.851 us; speedup vs baseline: 1.6881x; 1.6881x over previous
//
#include <hip/hip_runtime.h>
#include <math.h>

#define N_EMB   1000000
#define D       64
#define E_PAIRS 65536
#define K_NEG   16
#define P_TOTAL (E_PAIRS * (K_NEG + 1))   /* 1114112 */
#define PPB     128                        /* pairs per block */
#define XS      200                        /* LDS X row stride in bf16 elems (400B): 16B-aligned, 2-way bank alias (free) */

typedef __attribute__((ext_vector_type(8))) short  short8;
typedef __attribute__((ext_vector_type(4))) float  float4v;

static __device__ __forceinline__ unsigned short f2bf(float f) {
    unsigned int x = __float_as_uint(f);
    unsigned int r = (x + 0x7fffu + ((x >> 16) & 1u)) >> 16;   // RNE
    return (unsigned short)r;
}

__global__ __launch_bounds__(256)
void prep_kernel(const float* __restrict__ W1, unsigned short* __restrict__ W1bf)
{
    int i = blockIdx.x * 256 + threadIdx.x;
    if (i < 64 * 192) W1bf[i] = f2bf(W1[i]);
}

__global__ __launch_bounds__(256, 3)
void score_kernel(const float* __restrict__ embeds,
                  const int*   __restrict__ pos,
                  const int*   __restrict__ neg,
                  const unsigned short* __restrict__ W1bf,
                  const float* __restrict__ b1,
                  const float* __restrict__ W2,
                  const float* __restrict__ b2,
                  float*       __restrict__ scores)
{
    __shared__ unsigned short X[PPB * XS];   // [u(64) | v(64) | u*v(64)] bf16 per pair
    __shared__ int uidx[PPB];
    __shared__ int vidx[PPB];

    const int t = threadIdx.x;
    const int pbase = blockIdx.x * PPB;

    // ---- stage pair indices (block-uniform pos/neg branch: E_PAIRS % PPB == 0) ----
    if (t < PPB) {
        int p = pbase + t;
        int ui, vi;
        if (p < E_PAIRS) {
            ui = pos[2 * p];
            vi = pos[2 * p + 1];
        } else {
            int q = p - E_PAIRS;
            ui = neg[2 * q];
            vi = neg[2 * q + 1];
        }
        uidx[t] = ui;
        vidx[t] = vi;
    }
    __syncthreads();

    // ---- gather u,v (coalesced float4, 16 lanes per 256B row), fp32 product, bf16 -> LDS ----
    // 8 iters x 16 pairs: thread handles (pair pr, 4-float segment seg) of BOTH u and v.
    const int seg = t & 15;
    #pragma unroll
    for (int it = 0; it < 8; ++it) {
        int pr = it * 16 + (t >> 4);
        int ui = uidx[pr], vi = vidx[pr];
        float4 u4 = *(const float4*)(embeds + (long long)ui * D + seg * 4);
        float4 v4 = *(const float4*)(embeds + (long long)vi * D + seg * 4);
        float4 w4 = make_float4(u4.x * v4.x, u4.y * v4.y, u4.z * v4.z, u4.w * v4.w);

        union { unsigned short s[4]; uint2 v; } pu, pv, pw;
        pu.s[0] = f2bf(u4.x); pu.s[1] = f2bf(u4.y); pu.s[2] = f2bf(u4.z); pu.s[3] = f2bf(u4.w);
        pv.s[0] = f2bf(v4.x); pv.s[1] = f2bf(v4.y); pv.s[2] = f2bf(v4.z); pv.s[3] = f2bf(v4.w);
        pw.s[0] = f2bf(w4.x); pw.s[1] = f2bf(w4.y); pw.s[2] = f2bf(w4.z); pw.s[3] = f2bf(w4.w);

        unsigned short* xp = X + pr * XS + seg * 4;
        *(uint2*)(xp)       = pu.v;
        *(uint2*)(xp + 64)  = pv.v;
        *(uint2*)(xp + 128) = pw.v;
    }
    __syncthreads();

    // ---- MFMA: per wave, 32 pairs (2 m-tiles) x 64 outputs (4 n-tiles), K=192 (6 steps) ----
    const int lane = t & 63;
    const int wave = t >> 6;
    const int c16  = lane & 15;
    const int quad = lane >> 4;
    const int wp0  = wave * 32;

    float4v acc[2][4];
    #pragma unroll
    for (int mt = 0; mt < 2; ++mt)
        #pragma unroll
        for (int nt = 0; nt < 4; ++nt)
            acc[mt][nt] = (float4v){0.f, 0.f, 0.f, 0.f};

    #pragma unroll
    for (int ks = 0; ks < 6; ++ks) {
        const int koff = ks * 32 + quad * 8;
        short8 a0 = *(const short8*)(X + (wp0 + c16) * XS + koff);
        short8 a1 = *(const short8*)(X + (wp0 + 16 + c16) * XS + koff);
        short8 bfrag[4];
        #pragma unroll
        for (int nt = 0; nt < 4; ++nt)
            bfrag[nt] = *(const short8*)(W1bf + (nt * 16 + c16) * 192 + koff);
        #pragma unroll
        for (int nt = 0; nt < 4; ++nt) {
            acc[0][nt] = __builtin_amdgcn_mfma_f32_16x16x32_bf16(a0, bfrag[nt], acc[0][nt], 0, 0, 0);
            acc[1][nt] = __builtin_amdgcn_mfma_f32_16x16x32_bf16(a1, bfrag[nt], acc[1][nt], 0, 0, 0);
        }
    }

    // ---- epilogue: +b1, relu, dot W2, reduce over 16 n-lanes, sigmoid -> exp -> scores ----
    float b1v[4], w2v[4];
    #pragma unroll
    for (int nt = 0; nt < 4; ++nt) {
        b1v[nt] = b1[nt * 16 + c16];
        w2v[nt] = W2[nt * 16 + c16];
    }
    const float b2v = b2[0];

    #pragma unroll
    for (int mt = 0; mt < 2; ++mt) {
        #pragma unroll
        for (int reg = 0; reg < 4; ++reg) {
            float s = 0.f;
            #pragma unroll
            for (int nt = 0; nt < 4; ++nt) {
                float h = acc[mt][nt][reg] + b1v[nt];
                s += (h > 0.f ? h : 0.f) * w2v[nt];
            }
            s += __shfl_xor(s, 1);
            s += __shfl_xor(s, 2);
            s += __shfl_xor(s, 4);
            s += __shfl_xor(s, 8);
            if (c16 == 0) {
                float sig = 1.f / (1.f + expf(-(s + b2v)));
                scores[pbase + wp0 + mt * 16 + quad * 4 + reg] = expf(sig);
            }
        }
    }
}

__global__ __launch_bounds__(256)
void reduce_kernel(const float* __restrict__ scores, float* __restrict__ partials)
{
    __shared__ float sdata[256];
    int e = blockIdx.x * 256 + threadIdx.x;    // e in [0, E_PAIRS)
    float pos_s = scores[e];
    const float* ns = scores + E_PAIRS + (size_t)e * K_NEG;
    float nsum = 0.f;
    #pragma unroll
    for (int c = 0; c < 4; ++c) {
        float4 v = *(const float4*)(ns + c * 4);
        nsum += v.x + v.y + v.z + v.w;
    }
    float term = pos_s / (pos_s + nsum + 1e-8f) + 1e-8f;
    sdata[threadIdx.x] = term;
    __syncthreads();
    for (int s = 128; s > 0; s >>= 1) {
        if (threadIdx.x < s) sdata[threadIdx.x] += sdata[threadIdx.x + s];
        __syncthreads();
    }
    if (threadIdx.x == 0) partials[blockIdx.x] = sdata[0];
}

__global__ __launch_bounds__(256)
void final_kernel(const float* __restrict__ partials, float* __restrict__ out)
{
    __shared__ float sdata[256];
    sdata[threadIdx.x] = partials[threadIdx.x];
    __syncthreads();
    for (int s = 128; s > 0; s >>= 1) {
        if (threadIdx.x < s) sdata[threadIdx.x] += sdata[threadIdx.x + s];
        __syncthreads();
    }
    if (threadIdx.x == 0) out[0] = -sdata[0];
}

extern "C" void kernel_launch(void* const* d_in, const int* in_sizes, int n_in,
                              void* d_out, int out_size, void* d_ws, size_t ws_size,
                              hipStream_t stream)
{
    const float* embeds = (const float*)d_in[0];
    const int*   pos    = (const int*)d_in[1];
    const int*   neg    = (const int*)d_in[2];
    const float* W1     = (const float*)d_in[3];
    const float* b1     = (const float*)d_in[4];
    const float* W2     = (const float*)d_in[5];
    const float* b2     = (const float*)d_in[6];
    float* out = (float*)d_out;

    float* scores   = (float*)d_ws;                         // P_TOTAL floats
    float* partials = scores + P_TOTAL;                     // 256 floats
    unsigned short* W1bf = (unsigned short*)(partials + 256); // 64*192 bf16 (16B-aligned)

    prep_kernel<<<48, 256, 0, stream>>>(W1, W1bf);
    score_kernel<<<P_TOTAL / PPB, 256, 0, stream>>>(embeds, pos, neg, W1bf, b1, W2, b2, scores);
    reduce_kernel<<<E_PAIRS / 256, 256, 0, stream>>>(scores, partials);
    final_kernel<<<1, 256, 0, stream>>>(partials, out);
}